// Round 4
// baseline (171.322 us; speedup 1.0000x reference)
//
#include <hip/hip_runtime.h>
#include <cstddef>

namespace {
constexpr int B_   = 128;
constexpr int H_   = 256;
constexpr int HW   = 65536;        // 256*256
constexpr int EMB_ = 64;
constexpr int NF   = EMB_ + 18;    // 82
constexpr int BNF  = B_ * NF;      // 10496  ([n][m] layout: 82 rows x 128)
constexpr int KCH  = 1024;         // k-chunks (grid of stage 1)
constexpr int KC   = HW / KCH;     // 64 k per block
constexpr int KB   = 32;           // k per LDS stage (2 stages per block)
constexpr int XPAD = 36;           // xs row stride in words (bank-rotating, 16B-aligned)
constexpr int CB2  = 32;           // c-blocks in reduce level 1
}

// ---------------- Encoder stage 1: split-K ----------------
// 1024 blocks x 512 thr. Block = full 128m x 82n partial over its 64-k chunk.
// Wave-uniform n-block (21 cols): W_enc read via scalar loads -> SGPRs,
// FMA consumes SGPR operand directly. x staged in LDS [m][k], b128 reads.
// Waves: (wv>>2) -> m-half, (wv&3) -> n-block {0,21,42,61} (61/62 dup, benign).
__global__ __launch_bounds__(512) void enc_partial_k(
    const float* __restrict__ x, const float* __restrict__ Wenc,
    float* __restrict__ partialT)
{
    __shared__ __align__(16) float xs[128][XPAD];   // 18.4 KB
    const int tid  = threadIdx.x;
    const int lane = tid & 63;
    const int wv   = tid >> 6;
    const int k0   = blockIdx.x * KC;
    const int mh   = (wv >> 2) << 6;                // 0 or 64
    int n0i = (wv & 3) * 21; if (n0i > 61) n0i = 61;
    const int n0  = __builtin_amdgcn_readfirstlane(n0i);
    const int row = mh + lane;

    float acc[21];
#pragma unroll
    for (int j = 0; j < 21; ++j) acc[j] = 0.f;

    const int sm = tid >> 3;    // 0..63
    const int sf = tid & 7;     // 0..7  (8 x float4 = 32 k per row)

    for (int ks = 0; ks < KC; ks += KB) {
        __syncthreads();
#pragma unroll
        for (int p = 0; p < 2; ++p) {
            const int m = sm + (p << 6);
            const float4 v = *reinterpret_cast<const float4*>(
                &x[(size_t)m * HW + (size_t)(k0 + ks) + (sf << 2)]);
            *reinterpret_cast<float4*>(&xs[m][sf << 2]) = v;
        }
        __syncthreads();

#pragma unroll
        for (int kk4 = 0; kk4 < KB / 4; ++kk4) {
            const float4 xv = *reinterpret_cast<const float4*>(&xs[row][kk4 << 2]);
#pragma unroll
            for (int q = 0; q < 4; ++q) {
                const int k = k0 + ks + (kk4 << 2) + q;
                const float* __restrict__ wr = Wenc + (size_t)k * NF + n0;
                const float xq = (q == 0) ? xv.x : (q == 1) ? xv.y
                               : (q == 2) ? xv.z : xv.w;
                float w_[21];
#pragma unroll
                for (int j = 0; j < 21; ++j) w_[j] = wr[j];   // uniform -> s_load
#pragma unroll
                for (int j = 0; j < 21; ++j) acc[j] = fmaf(xq, w_[j], acc[j]);
            }
        }
    }

    // partialT layout: [block][n][m] -> coalesced 64-lane stores
    float* __restrict__ po = partialT + (size_t)blockIdx.x * BNF + mh + lane;
#pragma unroll
    for (int j = 0; j < 21; ++j) po[(size_t)(n0 + j) * B_] = acc[j];
}

// ---------------- Encoder reduce, level 1: 1024 -> 32 ----------------
__global__ __launch_bounds__(256) void enc_reduce1(
    const float* __restrict__ partialT, float* __restrict__ partial2)
{
    const int i = blockIdx.x * 256 + threadIdx.x;
    if (i >= BNF) return;
    const float* p = partialT + (size_t)blockIdx.y * (KCH / CB2) * BNF + i;
    float s = 0.f;
#pragma unroll 8
    for (int c = 0; c < KCH / CB2; ++c) s += p[(size_t)c * BNF];
    partial2[(size_t)blockIdx.y * BNF + i] = s;
}

// ---------------- Encoder reduce, level 2: 32 -> 1 (+bias) ----------------
// featsT layout: [n][m] (82 rows x 128)
__global__ __launch_bounds__(256) void enc_reduce2(
    const float* __restrict__ partial2, const float* __restrict__ benc,
    float* __restrict__ featsT)
{
    const int i = blockIdx.x * 256 + threadIdx.x;
    if (i >= BNF) return;
    float s = benc[i >> 7];
#pragma unroll
    for (int j = 0; j < CB2; ++j) s += partial2[(size_t)j * BNF + i];
    featsT[i] = s;
}

// ---------------- Decoder GEMM: pred = emb @ W_dec + b_dec ----------------
// 2048 blocks: blockIdx = mh*1024 + pb. Each block: 64 m-rows x 64-col tile.
// Thread tile 4m x 4p. embT staged coalesced from featsT rows (= emb^T).
__global__ __launch_bounds__(256) void decoder_k(
    const float* __restrict__ featsT, const float* __restrict__ Wdec,
    const float* __restrict__ bdec, float* __restrict__ pred)
{
    __shared__ float embT[EMB_][65];   // 16.6 KB
    const int tid   = threadIdx.x;
    const int pb    = blockIdx.x & 1023;
    const int mbase = (blockIdx.x >> 10) << 6;   // 0 or 64

    for (int i = tid; i < EMB_ * 64; i += 256) {
        const int k  = i >> 6;
        const int mm = i & 63;
        embT[k][mm] = featsT[(size_t)k * B_ + mbase + mm];
    }
    __syncthreads();

    const int tp = tid & 15;
    const int tm = tid >> 4;                 // 0..15
    const int p0 = pb * 64 + tp * 4;
    const int m0 = tm * 4;

    float acc[4][4];
#pragma unroll
    for (int i = 0; i < 4; ++i)
#pragma unroll
        for (int q = 0; q < 4; ++q) acc[i][q] = 0.f;

#pragma unroll 4
    for (int k = 0; k < EMB_; ++k) {
        const float4 w = *reinterpret_cast<const float4*>(&Wdec[(size_t)k * HW + p0]);
        float e[4];
#pragma unroll
        for (int i = 0; i < 4; ++i) e[i] = embT[k][m0 + i];
#pragma unroll
        for (int i = 0; i < 4; ++i) {
            acc[i][0] = fmaf(e[i], w.x, acc[i][0]);
            acc[i][1] = fmaf(e[i], w.y, acc[i][1]);
            acc[i][2] = fmaf(e[i], w.z, acc[i][2]);
            acc[i][3] = fmaf(e[i], w.w, acc[i][3]);
        }
    }
    const float4 bd = *reinterpret_cast<const float4*>(&bdec[p0]);
#pragma unroll
    for (int i = 0; i < 4; ++i) {
        float4 o;
        o.x = acc[i][0] + bd.x;
        o.y = acc[i][1] + bd.y;
        o.z = acc[i][2] + bd.z;
        o.w = acc[i][3] + bd.w;
        *reinterpret_cast<float4*>(&pred[(size_t)(mbase + m0 + i) * HW + p0]) = o;
    }
}

// ---------------- Bilinear affine grid-sample (zero padding) ----------------
__global__ __launch_bounds__(256) void gsample_k(
    const float* __restrict__ src, float* __restrict__ dst,
    const float* __restrict__ featsT, int theta_sel)
{
    const int b  = blockIdx.x >> 8;
    const int y  = blockIdx.x & 255;
    const int xq = threadIdx.x;

    const int tb = EMB_ + theta_sel * 6;
    const float t00 = featsT[(size_t)(tb + 0) * B_ + b];
    const float t01 = featsT[(size_t)(tb + 1) * B_ + b];
    const float t02 = featsT[(size_t)(tb + 2) * B_ + b];
    const float t10 = featsT[(size_t)(tb + 3) * B_ + b];
    const float t11 = featsT[(size_t)(tb + 4) * B_ + b];
    const float t12 = featsT[(size_t)(tb + 5) * B_ + b];

    const float X = (float)(2 * xq + 1) * (1.f / 256.f) - 1.f;
    const float Y = (float)(2 * y  + 1) * (1.f / 256.f) - 1.f;

    const float gx = t00 * X + t01 * Y + t02;
    const float gy = t10 * X + t11 * Y + t12;

    const float ix = (gx + 1.f) * 128.f - 0.5f;
    const float iy = (gy + 1.f) * 128.f - 0.5f;
    const float ix0 = floorf(ix);
    const float iy0 = floorf(iy);
    const float wx1 = ix - ix0, wx0 = 1.f - wx1;
    const float wy1 = iy - iy0, wy0 = 1.f - wy1;

    const float* sb = src + ((size_t)b << 16);
    auto tap = [&](float xf, float yf) -> float {
        const bool valid = (xf >= 0.f) && (xf < 256.f) &&
                           (yf >= 0.f) && (yf < 256.f);
        const int xi = (int)fminf(fmaxf(xf, 0.f), 255.f);
        const int yi = (int)fminf(fmaxf(yf, 0.f), 255.f);
        const float v = sb[(yi << 8) + xi];
        return valid ? v : 0.f;
    };
    const float v00 = tap(ix0,       iy0);
    const float v10 = tap(ix0 + 1.f, iy0);
    const float v01 = tap(ix0,       iy0 + 1.f);
    const float v11 = tap(ix0 + 1.f, iy0 + 1.f);

    dst[((size_t)blockIdx.x << 8) + xq] =
        v00 * (wx0 * wy0) + v10 * (wx1 * wy0) +
        v01 * (wx0 * wy1) + v11 * (wx1 * wy1);
}

extern "C" void kernel_launch(void* const* d_in, const int* in_sizes, int n_in,
                              void* d_out, int out_size, void* d_ws, size_t ws_size,
                              hipStream_t stream)
{
    const float* x    = (const float*)d_in[0];
    const float* Wenc = (const float*)d_in[1];
    const float* benc = (const float*)d_in[2];
    const float* Wdec = (const float*)d_in[3];
    const float* bdec = (const float*)d_in[4];
    float* out = (float*)d_out;

    float* ws       = (float*)d_ws;
    float* partialT = ws;                            // 1024*10496*4 = 43 MB
    float* imgA     = ws;                            // 33.5 MB, reused after reduce1 consumed partialT
    float* featsT   = ws + (size_t)KCH * BNF;        // after partialT (ws is 256 MiB)
    float* partial2 = out;                           // 32*10496 floats in d_out (overwritten later)

    enc_partial_k<<<KCH, 512, 0, stream>>>(x, Wenc, partialT);
    enc_reduce1<<<dim3((BNF + 255) / 256, CB2), 256, 0, stream>>>(partialT, partial2);
    enc_reduce2<<<(BNF + 255) / 256, 256, 0, stream>>>(partial2, benc, featsT);
    decoder_k<<<2048, 256, 0, stream>>>(featsT, Wdec, bdec, imgA);
    // reference order: grid_3 (translation), grid_1 (scaler_shear), grid_2 (rotation)
    gsample_k<<<B_ * H_, 256, 0, stream>>>(imgA, out, featsT, 2);
    gsample_k<<<B_ * H_, 256, 0, stream>>>(out, imgA, featsT, 0);
    gsample_k<<<B_ * H_, 256, 0, stream>>>(imgA, out, featsT, 1);
}

// Round 5
// 138.186 us; speedup vs baseline: 1.2398x; 1.2398x over previous
//
#include <hip/hip_runtime.h>
#include <cstddef>

namespace {
constexpr int B_   = 128;
constexpr int H_   = 256;
constexpr int HW   = 65536;        // 256*256
constexpr int EMB_ = 64;
constexpr int NF   = EMB_ + 18;    // 82
constexpr int BNF  = B_ * NF;      // 10496  ([n][m] layout: 82 rows x 128)
constexpr int KCH  = 512;          // k-chunks (grid of encoder)
constexpr int KC   = HW / KCH;     // 128 k per block
constexpr int WPITCH = 40;         // wT row pitch in bf16 (32 + 8 pad)
constexpr int CB2  = 32;           // groups in reduce level 1
}

typedef short  s16x4 __attribute__((ext_vector_type(4)));
typedef float  f32x4 __attribute__((ext_vector_type(4)));

__device__ __forceinline__ unsigned short bf16rn(float f) {
    unsigned u = __float_as_uint(f);
    u += 0x7FFFu + ((u >> 16) & 1u);
    return (unsigned short)(u >> 16);
}
__device__ __forceinline__ float bf16tof(unsigned short h) {
    return __uint_as_float(((unsigned)h) << 16);
}

// ---------------- Encoder: split-K bf16 MFMA ----------------
// 512 blocks x 512 thr (8 waves). Block = 128m x 82n partial over 128-k chunk.
// Wave wv owns m-subtile [wv*16, wv*16+16). x read global->regs directly
// (lines fully consumed per step). Wenc staged transposed bf16 hi/lo in LDS.
// n-tiles 0..3 (emb): hi*hi only. n-tiles 4,5 (theta): 3-term split.
// MFMA: D[n][m] with A[r=n][k]=Wenc[k][n], B[k][c=m]=x[m][k].
__global__ __launch_bounds__(512) void enc_mfma_k(
    const float* __restrict__ x, const float* __restrict__ Wenc,
    float* __restrict__ partialT)
{
    __shared__ __align__(16) unsigned short wH[96 * WPITCH];  // 7.5 KB
    __shared__ __align__(16) unsigned short wL[96 * WPITCH];  // 7.5 KB

    const int tid  = threadIdx.x;
    const int lane = tid & 63;
    const int wv   = tid >> 6;          // 0..7
    const int ln15 = lane & 15;
    const int lg   = lane >> 4;         // 0..3
    const int m0   = wv << 4;           // wave's m-subtile base
    const int kblk = blockIdx.x * KC;
    const float* __restrict__ xrow = x + (size_t)(m0 + ln15) * HW;

    f32x4 acc[6];
#pragma unroll
    for (int t = 0; t < 6; ++t) acc[t] = (f32x4){0.f, 0.f, 0.f, 0.f};

    for (int step = 0; step < KC / 32; ++step) {
        const int ks = kblk + step * 32;
        __syncthreads();   // previous step's LDS reads done before overwrite
        // stage Wenc[ks..ks+31][0..81] -> wT[n][kk] bf16 hi/lo
        for (int f = tid; f < 32 * NF; f += 512) {
            const int kk = f / NF;
            const int n  = f - NF * kk;
            const float w = Wenc[(size_t)(ks + kk) * NF + n];
            const unsigned short hi = bf16rn(w);
            const unsigned short lo = bf16rn(w - bf16tof(hi));
            wH[n * WPITCH + kk] = hi;
            wL[n * WPITCH + kk] = lo;
        }
        // x for this wave's B-frags (independent of LDS; overlaps staging)
        const float4 xa = *reinterpret_cast<const float4*>(&xrow[ks + lg * 4]);
        const float4 xb = *reinterpret_cast<const float4*>(&xrow[ks + 16 + lg * 4]);
        __syncthreads();

        s16x4 bh[2], bl[2];
        {
            const float xv[8] = {xa.x, xa.y, xa.z, xa.w, xb.x, xb.y, xb.z, xb.w};
#pragma unroll
            for (int s = 0; s < 2; ++s)
#pragma unroll
                for (int j = 0; j < 4; ++j) {
                    const float v = xv[s * 4 + j];
                    const unsigned short hi = bf16rn(v);
                    bh[s][j] = (short)hi;
                    bl[s][j] = (short)bf16rn(v - bf16tof(hi));
                }
        }

#pragma unroll
        for (int s = 0; s < 2; ++s) {
#pragma unroll
            for (int t = 0; t < 6; ++t) {
                const int aoff = (t * 16 + ln15) * WPITCH + s * 16 + lg * 4;
                const s16x4 ah = *reinterpret_cast<const s16x4*>(&wH[aoff]);
                acc[t] = __builtin_amdgcn_mfma_f32_16x16x16bf16_1k(
                    ah, bh[s], acc[t], 0, 0, 0);
                if (t >= 4) {   // theta tiles: add hi*lo + lo*hi
                    const s16x4 al = *reinterpret_cast<const s16x4*>(&wL[aoff]);
                    acc[t] = __builtin_amdgcn_mfma_f32_16x16x16bf16_1k(
                        ah, bl[s], acc[t], 0, 0, 0);
                    acc[t] = __builtin_amdgcn_mfma_f32_16x16x16bf16_1k(
                        al, bh[s], acc[t], 0, 0, 0);
                }
            }
        }
    }

    // store: D row = n-within-tile = lg*4+reg, col = m-within-tile = ln15
    float* __restrict__ base = partialT + (size_t)blockIdx.x * BNF;
#pragma unroll
    for (int t = 0; t < 5; ++t)
#pragma unroll
        for (int r = 0; r < 4; ++r) {
            const int n = t * 16 + lg * 4 + r;
            base[(size_t)n * B_ + m0 + ln15] = acc[t][r];
        }
    if (lg == 0) {  // tile 5: only n=80,81 valid
#pragma unroll
        for (int r = 0; r < 2; ++r)
            base[(size_t)(80 + r) * B_ + m0 + ln15] = acc[5][r];
    }
}

// ---------------- Encoder reduce, level 1: 512 -> 32 ----------------
__global__ __launch_bounds__(256) void enc_reduce1(
    const float* __restrict__ partialT, float* __restrict__ partial2)
{
    const int i = blockIdx.x * 256 + threadIdx.x;
    if (i >= BNF) return;
    const float* p = partialT + (size_t)blockIdx.y * (KCH / CB2) * BNF + i;
    float s = 0.f;
#pragma unroll 8
    for (int c = 0; c < KCH / CB2; ++c) s += p[(size_t)c * BNF];
    partial2[(size_t)blockIdx.y * BNF + i] = s;
}

// ---------------- Encoder reduce, level 2: 32 -> 1 (+bias) ----------------
// featsT layout: [n][m] (82 rows x 128)
__global__ __launch_bounds__(256) void enc_reduce2(
    const float* __restrict__ partial2, const float* __restrict__ benc,
    float* __restrict__ featsT)
{
    const int i = blockIdx.x * 256 + threadIdx.x;
    if (i >= BNF) return;
    float s = benc[i >> 7];
#pragma unroll
    for (int j = 0; j < CB2; ++j) s += partial2[(size_t)j * BNF + i];
    featsT[i] = s;
}

// ---------------- Decoder GEMM: pred = emb @ W_dec + b_dec ----------------
__global__ __launch_bounds__(256) void decoder_k(
    const float* __restrict__ featsT, const float* __restrict__ Wdec,
    const float* __restrict__ bdec, float* __restrict__ pred)
{
    __shared__ float embT[EMB_][65];   // 16.6 KB
    const int tid   = threadIdx.x;
    const int pb    = blockIdx.x & 1023;
    const int mbase = (blockIdx.x >> 10) << 6;   // 0 or 64

    for (int i = tid; i < EMB_ * 64; i += 256) {
        const int k  = i >> 6;
        const int mm = i & 63;
        embT[k][mm] = featsT[(size_t)k * B_ + mbase + mm];
    }
    __syncthreads();

    const int tp = tid & 15;
    const int tm = tid >> 4;                 // 0..15
    const int p0 = pb * 64 + tp * 4;
    const int m0 = tm * 4;

    float acc[4][4];
#pragma unroll
    for (int i = 0; i < 4; ++i)
#pragma unroll
        for (int q = 0; q < 4; ++q) acc[i][q] = 0.f;

#pragma unroll 4
    for (int k = 0; k < EMB_; ++k) {
        const float4 w = *reinterpret_cast<const float4*>(&Wdec[(size_t)k * HW + p0]);
        float e[4];
#pragma unroll
        for (int i = 0; i < 4; ++i) e[i] = embT[k][m0 + i];
#pragma unroll
        for (int i = 0; i < 4; ++i) {
            acc[i][0] = fmaf(e[i], w.x, acc[i][0]);
            acc[i][1] = fmaf(e[i], w.y, acc[i][1]);
            acc[i][2] = fmaf(e[i], w.z, acc[i][2]);
            acc[i][3] = fmaf(e[i], w.w, acc[i][3]);
        }
    }
    const float4 bd = *reinterpret_cast<const float4*>(&bdec[p0]);
#pragma unroll
    for (int i = 0; i < 4; ++i) {
        float4 o;
        o.x = acc[i][0] + bd.x;
        o.y = acc[i][1] + bd.y;
        o.z = acc[i][2] + bd.z;
        o.w = acc[i][3] + bd.w;
        *reinterpret_cast<float4*>(&pred[(size_t)(mbase + m0 + i) * HW + p0]) = o;
    }
}

// ---------------- Bilinear affine grid-sample (zero padding) ----------------
__global__ __launch_bounds__(256) void gsample_k(
    const float* __restrict__ src, float* __restrict__ dst,
    const float* __restrict__ featsT, int theta_sel)
{
    const int b  = blockIdx.x >> 8;
    const int y  = blockIdx.x & 255;
    const int xq = threadIdx.x;

    const int tb = EMB_ + theta_sel * 6;
    const float t00 = featsT[(size_t)(tb + 0) * B_ + b];
    const float t01 = featsT[(size_t)(tb + 1) * B_ + b];
    const float t02 = featsT[(size_t)(tb + 2) * B_ + b];
    const float t10 = featsT[(size_t)(tb + 3) * B_ + b];
    const float t11 = featsT[(size_t)(tb + 4) * B_ + b];
    const float t12 = featsT[(size_t)(tb + 5) * B_ + b];

    const float X = (float)(2 * xq + 1) * (1.f / 256.f) - 1.f;
    const float Y = (float)(2 * y  + 1) * (1.f / 256.f) - 1.f;

    const float gx = t00 * X + t01 * Y + t02;
    const float gy = t10 * X + t11 * Y + t12;

    const float ix = (gx + 1.f) * 128.f - 0.5f;
    const float iy = (gy + 1.f) * 128.f - 0.5f;
    const float ix0 = floorf(ix);
    const float iy0 = floorf(iy);
    const float wx1 = ix - ix0, wx0 = 1.f - wx1;
    const float wy1 = iy - iy0, wy0 = 1.f - wy1;

    const float* sb = src + ((size_t)b << 16);
    auto tap = [&](float xf, float yf) -> float {
        const bool valid = (xf >= 0.f) && (xf < 256.f) &&
                           (yf >= 0.f) && (yf < 256.f);
        const int xi = (int)fminf(fmaxf(xf, 0.f), 255.f);
        const int yi = (int)fminf(fmaxf(yf, 0.f), 255.f);
        const float v = sb[(yi << 8) + xi];
        return valid ? v : 0.f;
    };
    const float v00 = tap(ix0,       iy0);
    const float v10 = tap(ix0 + 1.f, iy0);
    const float v01 = tap(ix0,       iy0 + 1.f);
    const float v11 = tap(ix0 + 1.f, iy0 + 1.f);

    dst[((size_t)blockIdx.x << 8) + xq] =
        v00 * (wx0 * wy0) + v10 * (wx1 * wy0) +
        v01 * (wx0 * wy1) + v11 * (wx1 * wy1);
}

extern "C" void kernel_launch(void* const* d_in, const int* in_sizes, int n_in,
                              void* d_out, int out_size, void* d_ws, size_t ws_size,
                              hipStream_t stream)
{
    const float* x    = (const float*)d_in[0];
    const float* Wenc = (const float*)d_in[1];
    const float* benc = (const float*)d_in[2];
    const float* Wdec = (const float*)d_in[3];
    const float* bdec = (const float*)d_in[4];
    float* out = (float*)d_out;

    float* ws       = (float*)d_ws;
    float* partialT = ws;                      // 512*10496*4 = 21.5 MB
    float* imgA     = ws;                      // 33.5 MB (after reduce1 consumed partialT)
    float* featsT   = ws + (size_t)9 * 1024 * 1024;  // at 36 MB (clear of imgA)
    float* partial2 = out;                     // 32*10496 floats in d_out (overwritten later)

    enc_mfma_k<<<KCH, 512, 0, stream>>>(x, Wenc, partialT);
    enc_reduce1<<<dim3((BNF + 255) / 256, CB2), 256, 0, stream>>>(partialT, partial2);
    enc_reduce2<<<(BNF + 255) / 256, 256, 0, stream>>>(partial2, benc, featsT);
    decoder_k<<<2048, 256, 0, stream>>>(featsT, Wdec, bdec, imgA);
    // reference order: grid_3 (translation), grid_1 (scaler_shear), grid_2 (rotation)
    gsample_k<<<B_ * H_, 256, 0, stream>>>(imgA, out, featsT, 2);
    gsample_k<<<B_ * H_, 256, 0, stream>>>(out, imgA, featsT, 0);
    gsample_k<<<B_ * H_, 256, 0, stream>>>(imgA, out, featsT, 1);
}

// Round 6
// 137.524 us; speedup vs baseline: 1.2458x; 1.0048x over previous
//
#include <hip/hip_runtime.h>
#include <cstddef>

namespace {
constexpr int B_   = 128;
constexpr int HW   = 65536;        // 256*256
constexpr int EMB_ = 64;
constexpr int NF   = EMB_ + 18;    // 82
constexpr int BNF  = B_ * NF;      // 10496  ([n][m] layout)
constexpr int KCH  = 256;          // k-chunks (encoder grid)
constexpr int KC   = HW / KCH;     // 256 k per block
constexpr int NSTEP = KC / 32;     // 8 steps of 32 k
constexpr int WPITCH = 40;         // wT row pitch in bf16 (32 + 8 pad)
constexpr int CB2  = 32;           // groups in reduce level 1
}

typedef short  s16x4 __attribute__((ext_vector_type(4)));
typedef float  f32x4 __attribute__((ext_vector_type(4)));

__device__ __forceinline__ unsigned short bf16rn(float f) {
    unsigned u = __float_as_uint(f);
    u += 0x7FFFu + ((u >> 16) & 1u);
    return (unsigned short)(u >> 16);
}
__device__ __forceinline__ float bf16tof(unsigned short h) {
    return __uint_as_float(((unsigned)h) << 16);
}
__device__ __forceinline__ float ldpix(const unsigned short* p) { return bf16tof(*p); }
__device__ __forceinline__ float ldpix(const float* p)          { return *p; }
__device__ __forceinline__ void  stpix(unsigned short* p, float v) { *p = bf16rn(v); }
__device__ __forceinline__ void  stpix(float* p, float v)          { *p = v; }

// ---------------- Encoder: split-K bf16 MFMA ----------------
// 256 blocks x 512 thr (8 waves). Block = 128m x 82n partial over 256-k chunk.
// Wave wv owns m-subtile [wv*16, wv*16+16). x global->regs, double-buffered
// across steps. Wenc staged transposed bf16 hi/lo in LDS (vectorized).
// n-tiles 0..3 (emb): hi*hi only. n-tiles 4,5 (theta): 3-term split.
__global__ __launch_bounds__(512) void enc_mfma_k(
    const float* __restrict__ x, const float* __restrict__ Wenc,
    float* __restrict__ partialT)
{
    __shared__ __align__(16) unsigned short wH[96 * WPITCH];  // 7.5 KB
    __shared__ __align__(16) unsigned short wL[96 * WPITCH];  // 7.5 KB

    const int tid  = threadIdx.x;
    const int lane = tid & 63;
    const int wv   = tid >> 6;          // 0..7
    const int ln15 = lane & 15;
    const int lg   = lane >> 4;         // 0..3
    const int m0   = wv << 4;
    const int kblk = blockIdx.x * KC;
    const float* __restrict__ xrow = x + (size_t)(m0 + ln15) * HW + kblk;

    f32x4 acc[6];
#pragma unroll
    for (int t = 0; t < 6; ++t) acc[t] = (f32x4){0.f, 0.f, 0.f, 0.f};

    float4 xa = *reinterpret_cast<const float4*>(&xrow[lg * 4]);
    float4 xb = *reinterpret_cast<const float4*>(&xrow[16 + lg * 4]);

    for (int step = 0; step < NSTEP; ++step) {
        __syncthreads();   // prior step's LDS reads complete before overwrite
        // stage Wenc[32 rows x 82] -> wH/wL [n][kk], vectorized contiguous reads
        {
            const float4* wsrc = reinterpret_cast<const float4*>(
                Wenc + (size_t)(kblk + step * 32) * NF);
            for (int i4 = tid; i4 < (32 * NF) / 4; i4 += 512) {
                const float4 w4 = wsrc[i4];
                const float wv4[4] = {w4.x, w4.y, w4.z, w4.w};
#pragma unroll
                for (int j = 0; j < 4; ++j) {
                    const int idx = i4 * 4 + j;
                    const int kk  = idx / NF;
                    const int n   = idx - kk * NF;
                    const unsigned short hi = bf16rn(wv4[j]);
                    wH[n * WPITCH + kk] = hi;
                    wL[n * WPITCH + kk] = bf16rn(wv4[j] - bf16tof(hi));
                }
            }
        }
        // prefetch next step's x (independent of LDS; overlaps compute)
        float4 xa1, xb1;
        if (step + 1 < NSTEP) {
            xa1 = *reinterpret_cast<const float4*>(&xrow[(step + 1) * 32 + lg * 4]);
            xb1 = *reinterpret_cast<const float4*>(&xrow[(step + 1) * 32 + 16 + lg * 4]);
        }
        __syncthreads();

        s16x4 bh[2], bl[2];
        {
            const float xv[8] = {xa.x, xa.y, xa.z, xa.w, xb.x, xb.y, xb.z, xb.w};
#pragma unroll
            for (int s = 0; s < 2; ++s)
#pragma unroll
                for (int j = 0; j < 4; ++j) {
                    const float v = xv[s * 4 + j];
                    const unsigned short hi = bf16rn(v);
                    bh[s][j] = (short)hi;
                    bl[s][j] = (short)bf16rn(v - bf16tof(hi));
                }
        }

#pragma unroll
        for (int s = 0; s < 2; ++s) {
#pragma unroll
            for (int t = 0; t < 6; ++t) {
                const int aoff = (t * 16 + ln15) * WPITCH + s * 16 + lg * 4;
                const s16x4 ah = *reinterpret_cast<const s16x4*>(&wH[aoff]);
                acc[t] = __builtin_amdgcn_mfma_f32_16x16x16bf16_1k(
                    ah, bh[s], acc[t], 0, 0, 0);
                if (t >= 4) {
                    const s16x4 al = *reinterpret_cast<const s16x4*>(&wL[aoff]);
                    acc[t] = __builtin_amdgcn_mfma_f32_16x16x16bf16_1k(
                        ah, bl[s], acc[t], 0, 0, 0);
                    acc[t] = __builtin_amdgcn_mfma_f32_16x16x16bf16_1k(
                        al, bh[s], acc[t], 0, 0, 0);
                }
            }
        }
        if (step + 1 < NSTEP) { xa = xa1; xb = xb1; }
    }

    // store: D row = n-within-tile = lg*4+reg, col = m-within-tile = ln15
    float* __restrict__ base = partialT + (size_t)blockIdx.x * BNF;
#pragma unroll
    for (int t = 0; t < 5; ++t)
#pragma unroll
        for (int r = 0; r < 4; ++r) {
            const int n = t * 16 + lg * 4 + r;
            base[(size_t)n * B_ + m0 + ln15] = acc[t][r];
        }
    if (lg == 0) {
#pragma unroll
        for (int r = 0; r < 2; ++r)
            base[(size_t)(80 + r) * B_ + m0 + ln15] = acc[5][r];
    }
}

// ---------------- Encoder reduce, level 1: 256 -> 32 ----------------
__global__ __launch_bounds__(256) void enc_reduce1(
    const float* __restrict__ partialT, float* __restrict__ partial2)
{
    const int i = blockIdx.x * 256 + threadIdx.x;
    if (i >= BNF) return;
    const float* p = partialT + (size_t)blockIdx.y * (KCH / CB2) * BNF + i;
    float s = 0.f;
#pragma unroll
    for (int c = 0; c < KCH / CB2; ++c) s += p[(size_t)c * BNF];
    partial2[(size_t)blockIdx.y * BNF + i] = s;
}

// ---------------- Encoder reduce, level 2: 32 -> 1 (+bias) ----------------
__global__ __launch_bounds__(256) void enc_reduce2(
    const float* __restrict__ partial2, const float* __restrict__ benc,
    float* __restrict__ featsT)
{
    const int i = blockIdx.x * 256 + threadIdx.x;
    if (i >= BNF) return;
    float s = benc[i >> 7];
#pragma unroll
    for (int j = 0; j < CB2; ++j) s += partial2[(size_t)j * BNF + i];
    featsT[i] = s;
}

// ---------------- Decoder GEMM: pred = emb @ W_dec + b_dec (bf16 out) -------
// 1024 blocks x 512 thr: full 128 m x 64-col tile. Wdec read exactly once.
// Thread tile 4m x 4p. featsT rows 0..63 ARE embT [k][m] -> flat LDS copy.
__global__ __launch_bounds__(512) void decoder_k(
    const float* __restrict__ featsT, const float* __restrict__ Wdec,
    const float* __restrict__ bdec, unsigned short* __restrict__ pred)
{
    __shared__ float embT[EMB_ * B_];   // 32 KB, [k*128+m]
    const int tid = threadIdx.x;
    for (int i = tid; i < EMB_ * B_; i += 512) embT[i] = featsT[i];
    __syncthreads();

    const int tp = tid & 15;
    const int tm = tid >> 4;                 // 0..31
    const int p0 = blockIdx.x * 64 + tp * 4;
    const int m0 = tm * 4;

    float acc[4][4];
#pragma unroll
    for (int i = 0; i < 4; ++i)
#pragma unroll
        for (int q = 0; q < 4; ++q) acc[i][q] = 0.f;

#pragma unroll 4
    for (int k = 0; k < EMB_; ++k) {
        const float4 w = *reinterpret_cast<const float4*>(&Wdec[(size_t)k * HW + p0]);
        float e[4];
#pragma unroll
        for (int i = 0; i < 4; ++i) e[i] = embT[k * B_ + m0 + i];
#pragma unroll
        for (int i = 0; i < 4; ++i) {
            acc[i][0] = fmaf(e[i], w.x, acc[i][0]);
            acc[i][1] = fmaf(e[i], w.y, acc[i][1]);
            acc[i][2] = fmaf(e[i], w.z, acc[i][2]);
            acc[i][3] = fmaf(e[i], w.w, acc[i][3]);
        }
    }
    const float4 bd = *reinterpret_cast<const float4*>(&bdec[p0]);
#pragma unroll
    for (int i = 0; i < 4; ++i) {
        ushort4 o;
        o.x = bf16rn(acc[i][0] + bd.x);
        o.y = bf16rn(acc[i][1] + bd.y);
        o.z = bf16rn(acc[i][2] + bd.z);
        o.w = bf16rn(acc[i][3] + bd.w);
        *reinterpret_cast<ushort4*>(&pred[(size_t)(m0 + i) * HW + p0]) = o;
    }
}

// ---------------- Bilinear affine grid-sample (zero padding) ----------------
template <typename TI, typename TO>
__global__ __launch_bounds__(256) void gsample_k(
    const TI* __restrict__ src, TO* __restrict__ dst,
    const float* __restrict__ featsT, int theta_sel)
{
    const int b  = blockIdx.x >> 8;
    const int y  = blockIdx.x & 255;
    const int xq = threadIdx.x;

    const int tb = EMB_ + theta_sel * 6;
    const float t00 = featsT[(size_t)(tb + 0) * B_ + b];
    const float t01 = featsT[(size_t)(tb + 1) * B_ + b];
    const float t02 = featsT[(size_t)(tb + 2) * B_ + b];
    const float t10 = featsT[(size_t)(tb + 3) * B_ + b];
    const float t11 = featsT[(size_t)(tb + 4) * B_ + b];
    const float t12 = featsT[(size_t)(tb + 5) * B_ + b];

    const float X = (float)(2 * xq + 1) * (1.f / 256.f) - 1.f;
    const float Y = (float)(2 * y  + 1) * (1.f / 256.f) - 1.f;

    const float gx = t00 * X + t01 * Y + t02;
    const float gy = t10 * X + t11 * Y + t12;

    const float ix = (gx + 1.f) * 128.f - 0.5f;
    const float iy = (gy + 1.f) * 128.f - 0.5f;
    const float ix0 = floorf(ix);
    const float iy0 = floorf(iy);
    const float wx1 = ix - ix0, wx0 = 1.f - wx1;
    const float wy1 = iy - iy0, wy0 = 1.f - wy1;

    const TI* sb = src + ((size_t)b << 16);
    auto tap = [&](float xf, float yf) -> float {
        const bool valid = (xf >= 0.f) && (xf < 256.f) &&
                           (yf >= 0.f) && (yf < 256.f);
        const int xi = (int)fminf(fmaxf(xf, 0.f), 255.f);
        const int yi = (int)fminf(fmaxf(yf, 0.f), 255.f);
        const float v = ldpix(sb + (yi << 8) + xi);
        return valid ? v : 0.f;
    };
    const float v00 = tap(ix0,       iy0);
    const float v10 = tap(ix0 + 1.f, iy0);
    const float v01 = tap(ix0,       iy0 + 1.f);
    const float v11 = tap(ix0 + 1.f, iy0 + 1.f);

    stpix(dst + ((size_t)blockIdx.x << 8) + xq,
          v00 * (wx0 * wy0) + v10 * (wx1 * wy0) +
          v01 * (wx0 * wy1) + v11 * (wx1 * wy1));
}

extern "C" void kernel_launch(void* const* d_in, const int* in_sizes, int n_in,
                              void* d_out, int out_size, void* d_ws, size_t ws_size,
                              hipStream_t stream)
{
    const float* x    = (const float*)d_in[0];
    const float* Wenc = (const float*)d_in[1];
    const float* benc = (const float*)d_in[2];
    const float* Wdec = (const float*)d_in[3];
    const float* bdec = (const float*)d_in[4];
    float* out = (float*)d_out;

    char* wsb = (char*)d_ws;
    float* partialT         = (float*)wsb;                          // 10.7 MB (dead after reduce1)
    unsigned short* imgB0   = (unsigned short*)wsb;                 // 16.7 MB (written after partialT dead)
    unsigned short* imgB1   = (unsigned short*)(wsb + (20u << 20)); // 16.7 MB
    float* featsT           = (float*)(wsb + (40u << 20));          // 41 KB
    float* partial2         = out;                                  // 1.3 MB in d_out (overwritten by gs2)

    enc_mfma_k<<<KCH, 512, 0, stream>>>(x, Wenc, partialT);
    enc_reduce1<<<dim3((BNF + 255) / 256, CB2), 256, 0, stream>>>(partialT, partial2);
    enc_reduce2<<<(BNF + 255) / 256, 256, 0, stream>>>(partial2, benc, featsT);
    decoder_k<<<1024, 512, 0, stream>>>(featsT, Wdec, bdec, imgB0);
    // reference order: grid_3 (translation=2), grid_1 (scaler_shear=0), grid_2 (rotation=1)
    gsample_k<unsigned short, unsigned short>
        <<<B_ * 256, 256, 0, stream>>>(imgB0, imgB1, featsT, 2);
    gsample_k<unsigned short, unsigned short>
        <<<B_ * 256, 256, 0, stream>>>(imgB1, imgB0, featsT, 0);
    gsample_k<unsigned short, float>
        <<<B_ * 256, 256, 0, stream>>>(imgB0, out, featsT, 1);
}